// Round 1
// baseline (1271.110 us; speedup 1.0000x reference)
//
#include <hip/hip_runtime.h>

#define NN 100000     // nodes
#define NE 3200000    // edges
#define NG 512        // graphs
#define IND 128
#define H1D 32
#define H2D 16
#define BSH 7         // log2(bucket size)
#define BN  128       // nodes per bucket
#define NB  782       // ceil(NN/BN)

// ---------------- workspace layout (element offsets, 4B each) ----------------
#define O_DINV   0u          // float[100352]
#define O_BCNT   100352u     // int[1024]
#define O_BSTART 101376u     // int[1024] (need NB+1=783)
#define O_BCUR   102400u     // int[1024]
#define O_GSUM   103424u     // float[512]
#define O_GCNT   103936u     // float[512]
#define O_H1     104448u     // float[3200000]  h1 = x@W1
#define O_F1     3304448u    // float[3200000]  feat1 = relu(agg1+b1)
#define O_H2     6504448u    // float[1600000]  h2 = feat1@W2
#define O_CSR    8104448u    // u32[3200000]    binned packed edges
// total = 11,304,448 elems = 45.2 MB (<= previous 46.4 MB footprint)

__global__ __launch_bounds__(256) void k_init(int* bcnt, float* gsum, float* gcnt) {
    int i = blockIdx.x * 256 + threadIdx.x;
    if (i < 1024) bcnt[i] = 0;
    if (i < NG) { gsum[i] = 0.f; gcnt[i] = 0.f; }
}

// bucket counts via per-block LDS histogram (no scattered global atomics)
__global__ __launch_bounds__(256) void k_bcount(const int* __restrict__ dst,
                                                int* __restrict__ bcnt) {
    __shared__ int lc[NB];
    int t = threadIdx.x;
    for (int i = t; i < NB; i += 256) lc[i] = 0;
    __syncthreads();
    for (int e = blockIdx.x * 256 + t; e < NE; e += gridDim.x * 256)
        atomicAdd(&lc[dst[e] >> BSH], 1);
    __syncthreads();
    for (int i = t; i < NB; i += 256)
        if (lc[i]) atomicAdd(&bcnt[i], lc[i]);
}

// single-block scan of 782 bucket counts -> bucket starts + cursors
__global__ __launch_bounds__(1024) void k_bscan(const int* __restrict__ bcnt,
                                                int* __restrict__ bstart,
                                                int* __restrict__ bcur) {
    __shared__ int s[1024];
    int t = threadIdx.x;
    int v = (t < NB) ? bcnt[t] : 0;
    s[t] = v;
    __syncthreads();
    for (int off = 1; off < 1024; off <<= 1) {
        int u = (t >= off) ? s[t - off] : 0;
        __syncthreads();
        s[t] += u;
        __syncthreads();
    }
    int excl = s[t] - v;
    if (t < NB) { bstart[t] = excl; bcur[t] = excl; }
    if (t == NB - 1) bstart[NB] = s[t];   // = NE
}

// binned fill: per 8192-edge tile, LDS count -> per-bucket bump alloc -> place.
// Each bucket run is block-private & contiguous -> near-full-line HBM writes.
__global__ __launch_bounds__(256) void k_binfill(const int* __restrict__ src,
                                                 const int* __restrict__ dst,
                                                 int* __restrict__ bcur,
                                                 unsigned* __restrict__ csrb) {
    __shared__ int lc[NB];
    __shared__ int lbase[NB];
    int t = threadIdx.x;
    for (int i = t; i < NB; i += 256) lc[i] = 0;
    __syncthreads();
    int base = blockIdx.x << 13;
    int end = min(base + 8192, NE);
    for (int e = base + t; e < end; e += 256)
        atomicAdd(&lc[dst[e] >> BSH], 1);
    __syncthreads();
    for (int i = t; i < NB; i += 256) {
        int c = lc[i];
        lbase[i] = c ? atomicAdd(&bcur[i], c) : 0;
    }
    __syncthreads();
    for (int e = base + t; e < end; e += 256) {
        int d = dst[e];
        int b = d >> BSH;
        int p = atomicAdd(&lbase[b], 1);
        csrb[p] = (unsigned)src[e] | ((unsigned)(d & (BN - 1)) << 17);
    }
}

// per-bucket degree histogram from binned edges -> dinv (deg+1 for self-loop)
__global__ __launch_bounds__(256) void k_deg(const unsigned* __restrict__ csrb,
                                             const int* __restrict__ bstart,
                                             float* __restrict__ dinv) {
    __shared__ int h[BN];
    int t = threadIdx.x;
    if (t < BN) h[t] = 0;
    __syncthreads();
    int b = blockIdx.x;
    int bs_ = bstart[b], be = bstart[b + 1];
    for (int i = bs_ + t; i < be; i += 256)
        atomicAdd(&h[csrb[i] >> 17], 1);
    __syncthreads();
    int node = (b << BSH) + t;
    if (t < BN && node < NN)
        dinv[node] = 1.0f / sqrtf((float)(h[t] + 1));
}

// h1 = x @ W1 : [NN,128]x[128,32], float4 staging
__global__ __launch_bounds__(256) void k_gemm1(const float* __restrict__ x,
                                               const float* __restrict__ W1,
                                               float* __restrict__ h1) {
    __shared__ float sW[IND * H1D];   // 16 KB
    __shared__ float sX[8 * IND];     // 4 KB
    int t = threadIdx.x;
    const float4* w4 = (const float4*)W1;
    for (int i = t; i < IND * H1D / 4; i += 256) ((float4*)sW)[i] = w4[i];
    const float4* x4 = (const float4*)(x + (size_t)blockIdx.x * 8 * IND);
    ((float4*)sX)[t] = x4[t];                       // 256 float4 = 8 rows
    __syncthreads();
    int r = t >> 5, k = t & 31;
    float acc = 0.f;
#pragma unroll
    for (int i = 0; i < IND; ++i) acc += sX[r * IND + i] * sW[i * H1D + k];
    h1[((size_t)blockIdx.x * 8 + r) * H1D + k] = acc;
}

// layer-1 aggregate: one block per bucket, LDS accumulator [128][32]
__global__ __launch_bounds__(256) void k_agg1(const unsigned* __restrict__ csrb,
                                              const int* __restrict__ bstart,
                                              const float* __restrict__ h1,
                                              const float* __restrict__ dinv,
                                              const float* __restrict__ b1,
                                              float* __restrict__ feat1) {
    __shared__ float acc[BN * H1D];   // 16 KB
    int t = threadIdx.x;
    for (int i = t; i < BN * H1D; i += 256) acc[i] = 0.f;
    __syncthreads();
    int b = blockIdx.x;
    int bs_ = bstart[b], be = bstart[b + 1];
    int k = t & 31, slot = t >> 5;    // 8 edge slots x 32 feature lanes
    for (int i = bs_ + slot; i < be; i += 8) {
        unsigned p = csrb[i];
        int s = p & 0x1FFFF;
        int dl = p >> 17;
        atomicAdd(&acc[dl * H1D + k], h1[(size_t)s * H1D + k] * dinv[s]);
    }
    __syncthreads();
    int nn = min(BN, NN - (b << BSH));
    float bk = b1[t & 31];            // idx & 31 == t & 31 (stride 256)
    for (int idx = t; idx < nn * H1D; idx += 256) {
        int dl = idx >> 5;
        int d = (b << BSH) + dl;
        float dv = dinv[d];
        float v = acc[idx] * dv + h1[(size_t)d * H1D + (idx & 31)] * dv * dv + bk;
        feat1[(size_t)d * H1D + (idx & 31)] = fmaxf(v, 0.f);
    }
}

// h2 = feat1 @ W2 : [NN,32]x[32,16]
__global__ __launch_bounds__(256) void k_gemm2(const float* __restrict__ feat1,
                                               const float* __restrict__ W2,
                                               float* __restrict__ h2) {
    __shared__ float sW[H1D * H2D];
    int t = threadIdx.x;
    if (t < H1D * H2D / 4) ((float4*)sW)[t] = ((const float4*)W2)[t];
    __syncthreads();
    int idx = blockIdx.x * 256 + t;          // grid exact: NN*16/256
    int node = idx >> 4, k = idx & 15;
    const float* row = feat1 + (size_t)node * H1D;
    float a = 0.f;
#pragma unroll
    for (int i = 0; i < H1D; ++i) a += row[i] * sW[i * H2D + k];
    h2[idx] = a;
}

// layer-2 aggregate + bias + relu + dot(W3) + LDS graph accumulation
__global__ __launch_bounds__(256) void k_agg2(const unsigned* __restrict__ csrb,
                                              const int* __restrict__ bstart,
                                              const float* __restrict__ h2,
                                              const float* __restrict__ dinv,
                                              const float* __restrict__ b2,
                                              const float* __restrict__ W3,
                                              const int* __restrict__ batch,
                                              float* __restrict__ gsum,
                                              float* __restrict__ gcnt) {
    __shared__ float acc[BN * H2D];   // 8 KB
    __shared__ float gls[16], glc[16];
    int t = threadIdx.x;
    for (int i = t; i < BN * H2D; i += 256) acc[i] = 0.f;
    if (t < 16) { gls[t] = 0.f; glc[t] = 0.f; }
    __syncthreads();
    int b = blockIdx.x;
    int bs_ = bstart[b], be = bstart[b + 1];
    int k = t & 15, slot = t >> 4;    // 16 edge slots x 16 feature lanes
    for (int i = bs_ + slot; i < be; i += 16) {
        unsigned p = csrb[i];
        int s = p & 0x1FFFF;
        int dl = p >> 17;
        atomicAdd(&acc[dl * H2D + k], h2[(size_t)s * H2D + k] * dinv[s]);
    }
    __syncthreads();
    int nn = min(BN, NN - (b << BSH));   // 128 or 32 — both % 16 == 0
    int g0 = batch[b << BSH];            // batch sorted: bucket spans few graphs
    float w3 = W3[k];
    float bk = b2[k];
    for (int base = 0; base < nn; base += 16) {
        int dl = base + (t >> 4);
        int d = (b << BSH) + dl;
        float dv = dinv[d];
        float v = acc[dl * H2D + k] * dv + h2[(size_t)d * H2D + k] * dv * dv + bk;
        v = fmaxf(v, 0.f);
        float partial = v * w3;
        partial += __shfl_xor(partial, 1);
        partial += __shfl_xor(partial, 2);
        partial += __shfl_xor(partial, 4);
        partial += __shfl_xor(partial, 8);
        if (k == 0) {
            int g = batch[d];
            int rel = g - g0;
            if (rel >= 0 && rel < 16) {
                atomicAdd(&gls[rel], partial);
                atomicAdd(&glc[rel], 1.0f);
            } else {
                atomicAdd(&gsum[g], partial);
                atomicAdd(&gcnt[g], 1.0f);
            }
        }
    }
    __syncthreads();
    if (t < 16 && glc[t] > 0.f) {
        atomicAdd(&gsum[g0 + t], gls[t]);
        atomicAdd(&gcnt[g0 + t], glc[t]);
    }
}

__global__ __launch_bounds__(256) void k_final(const float* gsum, const float* gcnt,
                                               const float* b3, float* out) {
    int g = blockIdx.x * 256 + threadIdx.x;
    if (g < NG) out[g] = gsum[g] / fmaxf(gcnt[g], 1.0f) + b3[0];
}

extern "C" void kernel_launch(void* const* d_in, const int* in_sizes, int n_in,
                              void* d_out, int out_size, void* d_ws, size_t ws_size,
                              hipStream_t stream) {
    const float* x     = (const float*)d_in[0];
    const int*   src   = (const int*)d_in[1];
    const int*   dst   = src + NE;
    const int*   batch = (const int*)d_in[2];
    const float* W1 = (const float*)d_in[3];
    const float* b1 = (const float*)d_in[4];
    const float* W2 = (const float*)d_in[5];
    const float* b2 = (const float*)d_in[6];
    const float* W3 = (const float*)d_in[7];
    const float* b3 = (const float*)d_in[8];
    float* out = (float*)d_out;

    float* ws = (float*)d_ws;
    float*    dinv   = ws + O_DINV;
    int*      bcnt   = (int*)(ws + O_BCNT);
    int*      bstart = (int*)(ws + O_BSTART);
    int*      bcur   = (int*)(ws + O_BCUR);
    float*    gsum   = ws + O_GSUM;
    float*    gcnt   = ws + O_GCNT;
    float*    h1     = ws + O_H1;
    float*    feat1  = ws + O_F1;
    float*    h2     = ws + O_H2;
    unsigned* csrb   = (unsigned*)(ws + O_CSR);

    k_init   <<<4, 256, 0, stream>>>(bcnt, gsum, gcnt);
    k_bcount <<<512, 256, 0, stream>>>(dst, bcnt);
    k_bscan  <<<1, 1024, 0, stream>>>(bcnt, bstart, bcur);
    k_binfill<<<(NE + 8191) / 8192, 256, 0, stream>>>(src, dst, bcur, csrb);
    k_deg    <<<NB, 256, 0, stream>>>(csrb, bstart, dinv);

    k_gemm1  <<<NN / 8, 256, 0, stream>>>(x, W1, h1);
    k_agg1   <<<NB, 256, 0, stream>>>(csrb, bstart, h1, dinv, b1, feat1);
    k_gemm2  <<<NN * H2D / 256, 256, 0, stream>>>(feat1, W2, h2);
    k_agg2   <<<NB, 256, 0, stream>>>(csrb, bstart, h2, dinv, b2, W3, batch, gsum, gcnt);
    k_final  <<<2, 256, 0, stream>>>(gsum, gcnt, b3, out);
}

// Round 2
// 660.720 us; speedup vs baseline: 1.9238x; 1.9238x over previous
//
#include <hip/hip_runtime.h>

#define NN 100000     // nodes
#define NE 3200000    // edges
#define NG 512        // graphs
#define IND 128
#define H1D 32
#define H2D 16
#define BSH 7         // log2(bucket size)
#define BN  128       // nodes per bucket
#define NB  782       // ceil(NN/BN)

// ---------------- workspace layout (element offsets, 4B each) ----------------
#define O_DINV   0u          // float[100352]
#define O_ROW    100352u     // int[100352]  (needs NN+1)
#define O_BCNT   200704u     // int[1024]
#define O_BSTART 201728u     // int[1024] (need NB+1=783)
#define O_BCUR   202752u     // int[1024]
#define O_GSUM   203776u     // float[512]
#define O_GCNT   204288u     // float[512]
#define O_M1     204800u     // float[3200000]  m1 = (x@W1)*dinv
#define O_F1     3404800u    // u32[3200000] csrb (binned, temp) THEN float feat1
#define O_M2     6604800u    // float[1600000]  m2 = (feat1@W2)*dinv
#define O_CSR    8204800u    // int[3200000]    exact per-node CSR
// total = 11,404,800 elems = 45.6 MB

__global__ __launch_bounds__(256) void k_init(int* bcnt, float* gsum, float* gcnt) {
    int i = blockIdx.x * 256 + threadIdx.x;
    if (i < 1024) bcnt[i] = 0;
    if (i < NG) { gsum[i] = 0.f; gcnt[i] = 0.f; }
}

// bucket counts via per-block LDS histogram (no scattered global atomics)
__global__ __launch_bounds__(256) void k_bcount(const int* __restrict__ dst,
                                                int* __restrict__ bcnt) {
    __shared__ int lc[NB];
    int t = threadIdx.x;
    for (int i = t; i < NB; i += 256) lc[i] = 0;
    __syncthreads();
    for (int e = blockIdx.x * 256 + t; e < NE; e += gridDim.x * 256)
        atomicAdd(&lc[dst[e] >> BSH], 1);
    __syncthreads();
    for (int i = t; i < NB; i += 256)
        if (lc[i]) atomicAdd(&bcnt[i], lc[i]);
}

// single-block scan of 782 bucket counts -> bucket starts + cursors
__global__ __launch_bounds__(1024) void k_bscan(const int* __restrict__ bcnt,
                                                int* __restrict__ bstart,
                                                int* __restrict__ bcur) {
    __shared__ int s[1024];
    int t = threadIdx.x;
    int v = (t < NB) ? bcnt[t] : 0;
    s[t] = v;
    __syncthreads();
    for (int off = 1; off < 1024; off <<= 1) {
        int u = (t >= off) ? s[t - off] : 0;
        __syncthreads();
        s[t] += u;
        __syncthreads();
    }
    int excl = s[t] - v;
    if (t < NB) { bstart[t] = excl; bcur[t] = excl; }
    if (t == NB - 1) bstart[NB] = s[t];   // = NE
}

// binned fill: per 8192-edge tile, LDS count -> per-bucket bump alloc -> place.
// Each bucket run is block-private & contiguous -> near-full-line HBM writes.
__global__ __launch_bounds__(256) void k_binfill(const int* __restrict__ src,
                                                 const int* __restrict__ dst,
                                                 int* __restrict__ bcur,
                                                 unsigned* __restrict__ csrb) {
    __shared__ int lc[NB];
    __shared__ int lbase[NB];
    int t = threadIdx.x;
    for (int i = t; i < NB; i += 256) lc[i] = 0;
    __syncthreads();
    int base = blockIdx.x << 13;
    int end = min(base + 8192, NE);
    for (int e = base + t; e < end; e += 256)
        atomicAdd(&lc[dst[e] >> BSH], 1);
    __syncthreads();
    for (int i = t; i < NB; i += 256) {
        int c = lc[i];
        lbase[i] = c ? atomicAdd(&bcur[i], c) : 0;
    }
    __syncthreads();
    for (int e = base + t; e < end; e += 256) {
        int d = dst[e];
        int b = d >> BSH;
        int p = atomicAdd(&lbase[b], 1);
        csrb[p] = (unsigned)src[e] | ((unsigned)(d & (BN - 1)) << 17);
    }
}

// binned -> exact per-node CSR (block-local scatter within contiguous range),
// plus rowstart and dinv. One block per bucket.
__global__ __launch_bounds__(256) void k_reorder(const unsigned* __restrict__ csrb,
                                                 const int* __restrict__ bstart,
                                                 int* __restrict__ rowstart,
                                                 float* __restrict__ dinv,
                                                 int* __restrict__ csr) {
    __shared__ int h[BN];
    __shared__ int cur[BN];
    int t = threadIdx.x;
    if (t < BN) h[t] = 0;
    __syncthreads();
    int b = blockIdx.x;
    int bs_ = bstart[b], be = bstart[b + 1];
    for (int i = bs_ + t; i < be; i += 256)
        atomicAdd(&h[csrb[i] >> 17], 1);
    __syncthreads();
    int deg = (t < BN) ? h[t] : 0;
    for (int off = 1; off < BN; off <<= 1) {          // inclusive scan over 128
        int v = (t < BN && t >= off) ? h[t - off] : 0;
        __syncthreads();
        if (t < BN) h[t] += v;
        __syncthreads();
    }
    int excl = (t < BN) ? (h[t] - deg) : 0;
    if (t < BN) cur[t] = excl;
    int node = (b << BSH) + t;
    if (t < BN && node < NN) {
        rowstart[node] = bs_ + excl;
        dinv[node] = 1.0f / sqrtf((float)(deg + 1));  // +1 self-loop
    }
    if (b == NB - 1 && t == 0) rowstart[NN] = NE;
    __syncthreads();
    for (int i = bs_ + t; i < be; i += 256) {
        unsigned p = csrb[i];
        int dl = p >> 17;
        int pos = bs_ + atomicAdd(&cur[dl], 1);
        csr[pos] = (int)(p & 0x1FFFF);
    }
}

// m1 = (x @ W1) * dinv[node] : [NN,128]x[128,32]
__global__ __launch_bounds__(256) void k_gemm1(const float* __restrict__ x,
                                               const float* __restrict__ W1,
                                               const float* __restrict__ dinv,
                                               float* __restrict__ m1) {
    __shared__ float sW[IND * H1D];   // 16 KB
    __shared__ float sX[8 * IND];     // 4 KB
    int t = threadIdx.x;
    const float4* w4 = (const float4*)W1;
    for (int i = t; i < IND * H1D / 4; i += 256) ((float4*)sW)[i] = w4[i];
    const float4* x4 = (const float4*)(x + (size_t)blockIdx.x * 8 * IND);
    ((float4*)sX)[t] = x4[t];                       // 256 float4 = 8 rows
    __syncthreads();
    int r = t >> 5, k = t & 31;
    float acc = 0.f;
#pragma unroll
    for (int i = 0; i < IND; ++i) acc += sX[r * IND + i] * sW[i * H1D + k];
    int node = blockIdx.x * 8 + r;
    m1[(size_t)node * H1D + k] = acc * dinv[node];
}

// layer-1 aggregate, wave-per-node: v = (sum m1[s] + m1[d]) * dinv[d] + b1
__global__ __launch_bounds__(256) void k_agg1(const float* __restrict__ m1,
                                              const float* __restrict__ dinv,
                                              const int* __restrict__ rowstart,
                                              const int* __restrict__ csr,
                                              const float* __restrict__ b1,
                                              float* __restrict__ feat1) {
    int d = (blockIdx.x * 256 + threadIdx.x) >> 6;   // node id, 4 per block
    int lane = threadIdx.x & 63;
    int k = lane & 31, j = lane >> 5;
    int beg = rowstart[d], end = rowstart[d + 1];
    float acc = 0.f;
    for (int i = beg + j; i < end; i += 2) {
        int s = csr[i];
        acc += m1[(size_t)s * H1D + k];
    }
    acc += __shfl_xor(acc, 32);
    float v = (acc + m1[(size_t)d * H1D + k]) * dinv[d] + b1[k];
    if (j == 0) feat1[(size_t)d * H1D + k] = fmaxf(v, 0.f);
}

// m2 = (feat1 @ W2) * dinv[node] : [NN,32]x[32,16]
__global__ __launch_bounds__(256) void k_gemm2(const float* __restrict__ feat1,
                                               const float* __restrict__ W2,
                                               const float* __restrict__ dinv,
                                               float* __restrict__ m2) {
    __shared__ float sW[H1D * H2D];
    int t = threadIdx.x;
    if (t < H1D * H2D / 4) ((float4*)sW)[t] = ((const float4*)W2)[t];
    __syncthreads();
    int idx = blockIdx.x * 256 + t;          // grid exact: NN*16/256
    int node = idx >> 4, k = idx & 15;
    const float* row = feat1 + (size_t)node * H1D;
    float a = 0.f;
#pragma unroll
    for (int i = 0; i < H1D; ++i) a += row[i] * sW[i * H2D + k];
    m2[idx] = a * dinv[node];
}

// layer-2 aggregate + bias + relu + dot(W3) + scatter to graph accumulators
__global__ __launch_bounds__(256) void k_agg2(const float* __restrict__ m2,
                                              const float* __restrict__ dinv,
                                              const int* __restrict__ rowstart,
                                              const int* __restrict__ csr,
                                              const float* __restrict__ b2,
                                              const float* __restrict__ W3,
                                              const int* __restrict__ batch,
                                              float* __restrict__ gsum,
                                              float* __restrict__ gcnt) {
    int d = (blockIdx.x * 256 + threadIdx.x) >> 6;
    int lane = threadIdx.x & 63;
    int k = lane & 15, j = lane >> 4;
    int beg = rowstart[d], end = rowstart[d + 1];
    float acc = 0.f;
    for (int i = beg + j; i < end; i += 4) {
        int s = csr[i];
        acc += m2[(size_t)s * H2D + k];
    }
    acc += __shfl_xor(acc, 16);
    acc += __shfl_xor(acc, 32);
    float v = (acc + m2[(size_t)d * H2D + k]) * dinv[d] + b2[k];
    v = fmaxf(v, 0.f);
    float partial = v * W3[k];
    partial += __shfl_xor(partial, 1);
    partial += __shfl_xor(partial, 2);
    partial += __shfl_xor(partial, 4);
    partial += __shfl_xor(partial, 8);
    if (lane == 0) {
        int g = batch[d];
        atomicAdd(&gsum[g], partial);
        atomicAdd(&gcnt[g], 1.0f);
    }
}

__global__ __launch_bounds__(256) void k_final(const float* gsum, const float* gcnt,
                                               const float* b3, float* out) {
    int g = blockIdx.x * 256 + threadIdx.x;
    if (g < NG) out[g] = gsum[g] / fmaxf(gcnt[g], 1.0f) + b3[0];
}

extern "C" void kernel_launch(void* const* d_in, const int* in_sizes, int n_in,
                              void* d_out, int out_size, void* d_ws, size_t ws_size,
                              hipStream_t stream) {
    const float* x     = (const float*)d_in[0];
    const int*   src   = (const int*)d_in[1];
    const int*   dst   = src + NE;
    const int*   batch = (const int*)d_in[2];
    const float* W1 = (const float*)d_in[3];
    const float* b1 = (const float*)d_in[4];
    const float* W2 = (const float*)d_in[5];
    const float* b2 = (const float*)d_in[6];
    const float* W3 = (const float*)d_in[7];
    const float* b3 = (const float*)d_in[8];
    float* out = (float*)d_out;

    float* ws = (float*)d_ws;
    float*    dinv     = ws + O_DINV;
    int*      rowstart = (int*)(ws + O_ROW);
    int*      bcnt     = (int*)(ws + O_BCNT);
    int*      bstart   = (int*)(ws + O_BSTART);
    int*      bcur     = (int*)(ws + O_BCUR);
    float*    gsum     = ws + O_GSUM;
    float*    gcnt     = ws + O_GCNT;
    float*    m1       = ws + O_M1;
    unsigned* csrb     = (unsigned*)(ws + O_F1);   // temp, dead before feat1 written
    float*    feat1    = ws + O_F1;
    float*    m2       = ws + O_M2;
    int*      csr      = (int*)(ws + O_CSR);

    k_init   <<<4, 256, 0, stream>>>(bcnt, gsum, gcnt);
    k_bcount <<<512, 256, 0, stream>>>(dst, bcnt);
    k_bscan  <<<1, 1024, 0, stream>>>(bcnt, bstart, bcur);
    k_binfill<<<(NE + 8191) / 8192, 256, 0, stream>>>(src, dst, bcur, csrb);
    k_reorder<<<NB, 256, 0, stream>>>(csrb, bstart, rowstart, dinv, csr);

    k_gemm1  <<<NN / 8, 256, 0, stream>>>(x, W1, dinv, m1);
    k_agg1   <<<NN / 4, 256, 0, stream>>>(m1, dinv, rowstart, csr, b1, feat1);
    k_gemm2  <<<NN * H2D / 256, 256, 0, stream>>>(feat1, W2, dinv, m2);
    k_agg2   <<<NN / 4, 256, 0, stream>>>(m2, dinv, rowstart, csr, b2, W3, batch, gsum, gcnt);
    k_final  <<<2, 256, 0, stream>>>(gsum, gcnt, b3, out);
}

// Round 3
// 390.773 us; speedup vs baseline: 3.2528x; 1.6908x over previous
//
#include <hip/hip_runtime.h>

#define NN 100000     // nodes
#define NE 3200000    // edges
#define NG 512        // graphs
#define IND 128
#define H1D 32
#define H2D 16
#define BSH 7         // log2(bucket size)
#define BN  128       // nodes per bucket
#define NB  782       // ceil(NN/BN)

// ---------------- workspace layout (element offsets, 4B each) ----------------
#define O_DINV   0u          // float[100352]
#define O_ROW    100352u     // int[100352]  (needs NN+1)
#define O_BCNT   200704u     // int[1024]
#define O_BSTART 201728u     // int[1024] (need NB+1=783)
#define O_BCUR   202752u     // int[1024]
#define O_GSUM   203776u     // float[512]
#define O_GCNT   204288u     // float[512] (unused now)
#define O_M1     204800u     // float[3200000]  m1 = (x@W1)*dinv
#define O_F1     3404800u    // u32[3200000] csrb (binned, temp)
#define O_M2     6604800u    // float[1600000]  m2 = (relu(agg1)@W2)*dinv
#define O_CSR    8204800u    // int[3200000]    exact per-node CSR
// total = 11,404,800 elems = 45.6 MB

__global__ __launch_bounds__(256) void k_init(int* bcnt, float* gsum) {
    int i = blockIdx.x * 256 + threadIdx.x;
    if (i < 1024) bcnt[i] = 0;
    if (i < NG) gsum[i] = 0.f;
}

// bucket counts via per-block LDS histogram
__global__ __launch_bounds__(256) void k_bcount(const int* __restrict__ dst,
                                                int* __restrict__ bcnt) {
    __shared__ int lc[NB];
    int t = threadIdx.x;
    for (int i = t; i < NB; i += 256) lc[i] = 0;
    __syncthreads();
    for (int e = blockIdx.x * 256 + t; e < NE; e += gridDim.x * 256)
        atomicAdd(&lc[dst[e] >> BSH], 1);
    __syncthreads();
    for (int i = t; i < NB; i += 256)
        if (lc[i]) atomicAdd(&bcnt[i], lc[i]);
}

// single-block scan of bucket counts -> bucket starts + cursors
__global__ __launch_bounds__(1024) void k_bscan(const int* __restrict__ bcnt,
                                                int* __restrict__ bstart,
                                                int* __restrict__ bcur) {
    __shared__ int s[1024];
    int t = threadIdx.x;
    int v = (t < NB) ? bcnt[t] : 0;
    s[t] = v;
    __syncthreads();
    for (int off = 1; off < 1024; off <<= 1) {
        int u = (t >= off) ? s[t - off] : 0;
        __syncthreads();
        s[t] += u;
        __syncthreads();
    }
    int excl = s[t] - v;
    if (t < NB) { bstart[t] = excl; bcur[t] = excl; }
    if (t == NB - 1) bstart[NB] = s[t];   // = NE
}

// binned fill: per 8192-edge tile, LDS count -> per-bucket bump alloc -> place
__global__ __launch_bounds__(256) void k_binfill(const int* __restrict__ src,
                                                 const int* __restrict__ dst,
                                                 int* __restrict__ bcur,
                                                 unsigned* __restrict__ csrb) {
    __shared__ int lc[NB];
    __shared__ int lbase[NB];
    int t = threadIdx.x;
    for (int i = t; i < NB; i += 256) lc[i] = 0;
    __syncthreads();
    int base = blockIdx.x << 13;
    int end = min(base + 8192, NE);
    for (int e = base + t; e < end; e += 256)
        atomicAdd(&lc[dst[e] >> BSH], 1);
    __syncthreads();
    for (int i = t; i < NB; i += 256) {
        int c = lc[i];
        lbase[i] = c ? atomicAdd(&bcur[i], c) : 0;
    }
    __syncthreads();
    for (int e = base + t; e < end; e += 256) {
        int d = dst[e];
        int b = d >> BSH;
        int p = atomicAdd(&lbase[b], 1);
        csrb[p] = (unsigned)src[e] | ((unsigned)(d & (BN - 1)) << 17);
    }
}

// binned -> exact per-node CSR + rowstart + dinv. One block per bucket.
__global__ __launch_bounds__(256) void k_reorder(const unsigned* __restrict__ csrb,
                                                 const int* __restrict__ bstart,
                                                 int* __restrict__ rowstart,
                                                 float* __restrict__ dinv,
                                                 int* __restrict__ csr) {
    __shared__ int h[BN];
    __shared__ int cur[BN];
    int t = threadIdx.x;
    if (t < BN) h[t] = 0;
    __syncthreads();
    int b = blockIdx.x;
    int bs_ = bstart[b], be = bstart[b + 1];
    for (int i = bs_ + t; i < be; i += 256)
        atomicAdd(&h[csrb[i] >> 17], 1);
    __syncthreads();
    int deg = (t < BN) ? h[t] : 0;
    for (int off = 1; off < BN; off <<= 1) {
        int v = (t < BN && t >= off) ? h[t - off] : 0;
        __syncthreads();
        if (t < BN) h[t] += v;
        __syncthreads();
    }
    int excl = (t < BN) ? (h[t] - deg) : 0;
    if (t < BN) cur[t] = excl;
    int node = (b << BSH) + t;
    if (t < BN && node < NN) {
        rowstart[node] = bs_ + excl;
        dinv[node] = 1.0f / sqrtf((float)(deg + 1));  // +1 self-loop
    }
    if (b == NB - 1 && t == 0) rowstart[NN] = NE;
    __syncthreads();
    for (int i = bs_ + t; i < be; i += 256) {
        unsigned p = csrb[i];
        int dl = p >> 17;
        int pos = bs_ + atomicAdd(&cur[dl], 1);
        csr[pos] = (int)(p & 0x1FFFF);
    }
}

// m1 = (x @ W1) * dinv : [NN,128]x[128,32]; 16 nodes/block, 2 nodes/thread,
// all LDS traffic as ds_read_b128 (transposed padded W)
__global__ __launch_bounds__(256) void k_gemm1(const float* __restrict__ x,
                                               const float* __restrict__ W1,
                                               const float* __restrict__ dinv,
                                               float* __restrict__ m1) {
    __shared__ float sWt[32 * 132];   // W1^T [k][i], pad 4 -> 16B-aligned rows
    __shared__ float sX[16 * IND];    // 8 KB
    int t = threadIdx.x;
    for (int idx = t; idx < IND * H1D; idx += 256) {
        int i = idx >> 5, k = idx & 31;
        sWt[k * 132 + i] = W1[idx];   // W1[i][k]
    }
    const float4* x4 = (const float4*)(x + (size_t)blockIdx.x * 16 * IND);
    ((float4*)sX)[t] = x4[t];
    ((float4*)sX)[t + 256] = x4[t + 256];
    __syncthreads();
    int r = t >> 5, k = t & 31;
    float a0 = 0.f, a1 = 0.f;
#pragma unroll
    for (int i = 0; i < IND; i += 4) {
        float4 w = *(const float4*)&sWt[k * 132 + i];
        float4 p = *(const float4*)&sX[r * IND + i];
        float4 s = *(const float4*)&sX[(r + 8) * IND + i];
        a0 += p.x * w.x + p.y * w.y + p.z * w.z + p.w * w.w;
        a1 += s.x * w.x + s.y * w.y + s.z * w.z + s.w * w.w;
    }
    int n0 = blockIdx.x * 16 + r;
    m1[(size_t)n0 * H1D + k] = a0 * dinv[n0];
    m1[(size_t)(n0 + 8) * H1D + k] = a1 * dinv[n0 + 8];
}

// layer-1 aggregate + relu + FUSED gemm2 -> m2 = (relu(.)@W2)*dinv
// wave per node; lane = slot j (0..7) x feature-quad q (0..7); float4 gathers
__global__ __launch_bounds__(256) void k_agg1(const float* __restrict__ m1,
                                              const float* __restrict__ dinv,
                                              const int* __restrict__ rowstart,
                                              const int* __restrict__ csr,
                                              const float* __restrict__ b1,
                                              const float* __restrict__ W2,
                                              float* __restrict__ m2) {
    int t = threadIdx.x;
    int d = (blockIdx.x * 256 + t) >> 6;
    int lane = t & 63;
    int q = lane & 7;
    int j = lane >> 3;
    int beg = rowstart[d], end = rowstart[d + 1];
    float dv = dinv[d];
    const float4* m1_4 = (const float4*)m1;
    float4 self = m1_4[(size_t)d * 8 + q];
    float ax = 0.f, ay = 0.f, az = 0.f, aw = 0.f;
    int i = beg + j;
    for (; i + 8 < end; i += 16) {       // 2x unroll: 2 csr + 2 gathers in flight
        int s0 = csr[i], s1 = csr[i + 8];
        float4 a = m1_4[(size_t)s0 * 8 + q];
        float4 b = m1_4[(size_t)s1 * 8 + q];
        ax += a.x + b.x; ay += a.y + b.y;
        az += a.z + b.z; aw += a.w + b.w;
    }
    if (i < end) {
        int s = csr[i];
        float4 a = m1_4[(size_t)s * 8 + q];
        ax += a.x; ay += a.y; az += a.z; aw += a.w;
    }
#pragma unroll
    for (int m = 8; m <= 32; m <<= 1) {  // reduce over edge slots (bits 3..5)
        ax += __shfl_xor(ax, m); ay += __shfl_xor(ay, m);
        az += __shfl_xor(az, m); aw += __shfl_xor(aw, m);
    }
    float4 bq = ((const float4*)b1)[q];
    float vx = fmaxf((ax + self.x) * dv + bq.x, 0.f);
    float vy = fmaxf((ay + self.y) * dv + bq.y, 0.f);
    float vz = fmaxf((az + self.z) * dv + bq.z, 0.f);
    float vw = fmaxf((aw + self.w) * dv + bq.w, 0.f);
    // fused 32x16 matvec: this lane covers features 4q..4q+3, outputs 2j,2j+1
    int f0 = q * 4;
    const float2* W2_2 = (const float2*)W2;   // W2[f][o]: pair idx = f*8 + j
    float2 w0 = W2_2[(f0    ) * 8 + j];
    float2 w1 = W2_2[(f0 + 1) * 8 + j];
    float2 w2 = W2_2[(f0 + 2) * 8 + j];
    float2 w3 = W2_2[(f0 + 3) * 8 + j];
    float p0 = vx * w0.x + vy * w1.x + vz * w2.x + vw * w3.x;
    float p1 = vx * w0.y + vy * w1.y + vz * w2.y + vw * w3.y;
#pragma unroll
    for (int m = 1; m <= 4; m <<= 1) {   // reduce over q (bits 0..2)
        p0 += __shfl_xor(p0, m);
        p1 += __shfl_xor(p1, m);
    }
    if (q == 0) {
        float2 r; r.x = p0 * dv; r.y = p1 * dv;
        ((float2*)m2)[(size_t)d * 8 + j] = r;
    }
}

// layer-2 aggregate + bias + relu + dot(W3) + block-combined graph scatter
// wave per node; lane = slot j (0..15) x quad q (0..3); float4 gathers
__global__ __launch_bounds__(256) void k_agg2(const float* __restrict__ m2,
                                              const float* __restrict__ dinv,
                                              const int* __restrict__ rowstart,
                                              const int* __restrict__ csr,
                                              const float* __restrict__ b2,
                                              const float* __restrict__ W3,
                                              const int* __restrict__ batch,
                                              float* __restrict__ gsum) {
    __shared__ float bsum[4];
    __shared__ int   bg[4];
    int t = threadIdx.x;
    int d = (blockIdx.x * 256 + t) >> 6;
    int lane = t & 63;
    int q = lane & 3;
    int j = lane >> 2;
    int beg = rowstart[d], end = rowstart[d + 1];
    float dv = dinv[d];
    const float4* m2_4 = (const float4*)m2;
    float4 self = m2_4[(size_t)d * 4 + q];
    float ax = 0.f, ay = 0.f, az = 0.f, aw = 0.f;
    int i = beg + j;
    for (; i + 16 < end; i += 32) {
        int s0 = csr[i], s1 = csr[i + 16];
        float4 a = m2_4[(size_t)s0 * 4 + q];
        float4 b = m2_4[(size_t)s1 * 4 + q];
        ax += a.x + b.x; ay += a.y + b.y;
        az += a.z + b.z; aw += a.w + b.w;
    }
    if (i < end) {
        int s = csr[i];
        float4 a = m2_4[(size_t)s * 4 + q];
        ax += a.x; ay += a.y; az += a.z; aw += a.w;
    }
#pragma unroll
    for (int m = 4; m <= 32; m <<= 1) {  // reduce over edge slots (bits 2..5)
        ax += __shfl_xor(ax, m); ay += __shfl_xor(ay, m);
        az += __shfl_xor(az, m); aw += __shfl_xor(aw, m);
    }
    float4 bq = ((const float4*)b2)[q];
    float4 wq = ((const float4*)W3)[q];
    float v0 = fmaxf((ax + self.x) * dv + bq.x, 0.f);
    float v1 = fmaxf((ay + self.y) * dv + bq.y, 0.f);
    float v2 = fmaxf((az + self.z) * dv + bq.z, 0.f);
    float v3 = fmaxf((aw + self.w) * dv + bq.w, 0.f);
    float partial = v0 * wq.x + v1 * wq.y + v2 * wq.z + v3 * wq.w;
    partial += __shfl_xor(partial, 1);
    partial += __shfl_xor(partial, 2);
    int w = t >> 6;
    if (lane == 0) { bg[w] = batch[d]; bsum[w] = partial; }
    __syncthreads();
    if (t == 0) {      // combine the block's 4 nodes (batch sorted -> few graphs)
        float s = bsum[0]; int g = bg[0];
#pragma unroll
        for (int u = 1; u < 4; ++u) {
            if (bg[u] == g) s += bsum[u];
            else { atomicAdd(&gsum[g], s); g = bg[u]; s = bsum[u]; }
        }
        atomicAdd(&gsum[g], s);
    }
}

// counts via binary search on sorted batch (no gcnt atomics)
__global__ __launch_bounds__(256) void k_final(const float* __restrict__ gsum,
                                               const int* __restrict__ batch,
                                               const float* __restrict__ b3,
                                               float* __restrict__ out) {
    int g = blockIdx.x * 256 + threadIdx.x;
    if (g >= NG) return;
    int lo = 0, hi = NN;
    while (lo < hi) { int mid = (lo + hi) >> 1; if (batch[mid] < g) lo = mid + 1; else hi = mid; }
    int lo2 = lo, hi2 = NN;
    while (lo2 < hi2) { int mid = (lo2 + hi2) >> 1; if (batch[mid] < g + 1) lo2 = mid + 1; else hi2 = mid; }
    out[g] = gsum[g] / fmaxf((float)(lo2 - lo), 1.0f) + b3[0];
}

extern "C" void kernel_launch(void* const* d_in, const int* in_sizes, int n_in,
                              void* d_out, int out_size, void* d_ws, size_t ws_size,
                              hipStream_t stream) {
    const float* x     = (const float*)d_in[0];
    const int*   src   = (const int*)d_in[1];
    const int*   dst   = src + NE;
    const int*   batch = (const int*)d_in[2];
    const float* W1 = (const float*)d_in[3];
    const float* b1 = (const float*)d_in[4];
    const float* W2 = (const float*)d_in[5];
    const float* b2 = (const float*)d_in[6];
    const float* W3 = (const float*)d_in[7];
    const float* b3 = (const float*)d_in[8];
    float* out = (float*)d_out;

    float* ws = (float*)d_ws;
    float*    dinv     = ws + O_DINV;
    int*      rowstart = (int*)(ws + O_ROW);
    int*      bcnt     = (int*)(ws + O_BCNT);
    int*      bstart   = (int*)(ws + O_BSTART);
    int*      bcur     = (int*)(ws + O_BCUR);
    float*    gsum     = ws + O_GSUM;
    float*    m1       = ws + O_M1;
    unsigned* csrb     = (unsigned*)(ws + O_F1);   // temp
    float*    m2       = ws + O_M2;
    int*      csr      = (int*)(ws + O_CSR);

    k_init   <<<4, 256, 0, stream>>>(bcnt, gsum);
    k_bcount <<<512, 256, 0, stream>>>(dst, bcnt);
    k_bscan  <<<1, 1024, 0, stream>>>(bcnt, bstart, bcur);
    k_binfill<<<(NE + 8191) / 8192, 256, 0, stream>>>(src, dst, bcur, csrb);
    k_reorder<<<NB, 256, 0, stream>>>(csrb, bstart, rowstart, dinv, csr);

    k_gemm1  <<<NN / 16, 256, 0, stream>>>(x, W1, dinv, m1);
    k_agg1   <<<NN / 4, 256, 0, stream>>>(m1, dinv, rowstart, csr, b1, W2, m2);
    k_agg2   <<<NN / 4, 256, 0, stream>>>(m2, dinv, rowstart, csr, b2, W3, batch, gsum);
    k_final  <<<2, 256, 0, stream>>>(gsum, batch, b3, out);
}